// Round 1
// baseline (1127.494 us; speedup 1.0000x reference)
//
#include <hip/hip_runtime.h>
#include <math.h>

// Problem dims (fixed by setup_inputs)
#define B_LAB 1024
#define B_TOT 2048
#define CDIM  1024
#define DDIM  784
#define H1DIM 512
#define H2DIM 128
#define ADIM  32
#define NADIM 64

// ---------------------------------------------------------------------------
// GEMM: out[m,n] = act( sum_k A(m,k) * W[n,k] + bias[n] )
// A rows come from A0 (first rows0 rows) then A1 (remaining rows) so we can
// process x and x_unlab in one pass without a concat copy.
// 64x64 tile, BK=16, 256 threads, 4x4 per thread. fp32.
// ---------------------------------------------------------------------------
template <int RELU>
__global__ __launch_bounds__(256) void gemm_xwt(
    const float* __restrict__ A0, const float* __restrict__ A1, int rows0,
    const float* __restrict__ W, const float* __restrict__ bias,
    float* __restrict__ out, int M, int N, int K)
{
    __shared__ float As[16][68];   // [kk][mm], pad to 68 (16B-aligned rows, conflict-free)
    __shared__ float Ws[16][68];

    const int tid = threadIdx.x;
    const int tx = tid & 15, ty = tid >> 4;
    const int m0 = blockIdx.y * 64, n0 = blockIdx.x * 64;

    float acc[4][4] = {};

    for (int k0 = 0; k0 < K; k0 += 16) {
        #pragma unroll
        for (int l = 0; l < 4; ++l) {
            int linear = tid + l * 256;          // 0..1023
            int kk = linear & 15, mm = linear >> 4;
            int m = m0 + mm;
            const float* srcA = (m < rows0) ? (A0 + (size_t)m * K)
                                            : (A1 + (size_t)(m - rows0) * K);
            As[kk][mm] = srcA[k0 + kk];
            Ws[kk][mm] = W[(size_t)(n0 + mm) * K + (k0 + kk)];
        }
        __syncthreads();
        #pragma unroll
        for (int kk = 0; kk < 16; ++kk) {
            float a[4], w[4];
            #pragma unroll
            for (int i = 0; i < 4; ++i) a[i] = As[kk][ty * 4 + i];
            #pragma unroll
            for (int j = 0; j < 4; ++j) w[j] = Ws[kk][tx * 4 + j];
            #pragma unroll
            for (int i = 0; i < 4; ++i)
                #pragma unroll
                for (int j = 0; j < 4; ++j)
                    acc[i][j] = fmaf(a[i], w[j], acc[i][j]);
        }
        __syncthreads();
    }

    #pragma unroll
    for (int i = 0; i < 4; ++i) {
        int m = m0 + ty * 4 + i;
        #pragma unroll
        for (int j = 0; j < 4; ++j) {
            int n = n0 + tx * 4 + j;
            float v = acc[i][j] + bias[n];
            if (RELU) v = fmaxf(v, 0.f);
            out[(size_t)m * N + n] = v;
        }
    }
}

// ---------------------------------------------------------------------------
// BCEWithLogits sum over labeled rows: sum softplus(z) - z[b, y[b]]
// ---------------------------------------------------------------------------
__global__ __launch_bounds__(256) void ce_kernel(
    const float* __restrict__ OUT, const int* __restrict__ y,
    float* __restrict__ acc)
{
    float local = 0.f;
    const size_t total = (size_t)B_LAB * CDIM;
    for (size_t idx = (size_t)blockIdx.x * 256 + threadIdx.x; idx < total;
         idx += (size_t)gridDim.x * 256) {
        int b = (int)(idx >> 10);
        int c = (int)(idx & 1023);
        float z = OUT[idx];
        // stable softplus
        float sp = fmaxf(z, 0.f) + log1pf(expf(-fabsf(z)));
        if (c == y[b]) sp -= z;
        local += sp;
    }
    // wave reduce (64 lanes)
    for (int off = 32; off; off >>= 1) local += __shfl_down(local, off);
    __shared__ float part[4];
    int lane = threadIdx.x & 63, wv = threadIdx.x >> 6;
    if (lane == 0) part[wv] = local;
    __syncthreads();
    if (threadIdx.x == 0)
        atomicAdd(acc, part[0] + part[1] + part[2] + part[3]);
}

// ---------------------------------------------------------------------------
// Semantic loss: 8 batch-rows per block. Stage logp / log1mp in LDS, then
// gather-sum per class, exp-clamp, block-reduce, -log(min(sum,1)).
// ---------------------------------------------------------------------------
__global__ __launch_bounds__(256) void sem_loss_kernel(
    const float* __restrict__ OUT, const int* __restrict__ aidx,
    const int* __restrict__ nidx, float* __restrict__ acc)
{
    __shared__ float lp[8][1024];
    __shared__ float l1p[8][1024];
    __shared__ float red[64];     // 4 waves x 16 values
    __shared__ float rowsum[16];

    const int tid = threadIdx.x;
    const int b0 = blockIdx.x * 8;

    // Phase 1: logits -> logp / log1mp in LDS
    for (int idx = tid; idx < 8 * 1024; idx += 256) {
        int r = idx >> 10, c = idx & 1023;
        float z = OUT[(size_t)(b0 + r) * CDIM + c];
        float p = 1.f / (1.f + expf(-z));
        lp[r][c]  = logf(p + 1e-9f);
        l1p[r][c] = logf(1.f - p + 1e-9f);
    }
    __syncthreads();

    // Phase 2: each thread handles 4 classes x 8 rows
    float e1[8] = {}, e2[8] = {};
    #pragma unroll
    for (int c4 = 0; c4 < 4; ++c4) {
        int i = tid + c4 * 256;
        const int4* arow = (const int4*)(aidx + i * ADIM);
        float s[8] = {};
        #pragma unroll
        for (int a4 = 0; a4 < ADIM / 4; ++a4) {
            int4 kv = arow[a4];
            #pragma unroll
            for (int r = 0; r < 8; ++r)
                s[r] += lp[r][kv.x] + lp[r][kv.y] + lp[r][kv.z] + lp[r][kv.w];
        }
        #pragma unroll
        for (int r = 0; r < 8; ++r) e1[r] += expf(fminf(s[r], 5.f));

        const int4* nrow = (const int4*)(nidx + i * NADIM);
        float t[8] = {};
        #pragma unroll
        for (int a4 = 0; a4 < NADIM / 4; ++a4) {
            int4 kv = nrow[a4];
            #pragma unroll
            for (int r = 0; r < 8; ++r)
                t[r] += l1p[r][kv.x] + l1p[r][kv.y] + l1p[r][kv.z] + l1p[r][kv.w];
        }
        #pragma unroll
        for (int r = 0; r < 8; ++r) e2[r] += expf(fminf(t[r], 5.f));
    }

    // Phase 3: block-reduce the 16 per-thread accumulators
    int lane = tid & 63, wv = tid >> 6;
    #pragma unroll
    for (int r = 0; r < 8; ++r) {
        float v1 = e1[r], v2 = e2[r];
        for (int off = 32; off; off >>= 1) {
            v1 += __shfl_down(v1, off);
            v2 += __shfl_down(v2, off);
        }
        if (lane == 0) { red[wv * 16 + r * 2] = v1; red[wv * 16 + r * 2 + 1] = v2; }
    }
    __syncthreads();
    if (tid < 16)
        rowsum[tid] = red[tid] + red[16 + tid] + red[32 + tid] + red[48 + tid];
    __syncthreads();
    if (tid < 8) {
        float s1 = fminf(rowsum[tid * 2], 1.f);
        float s2 = fminf(rowsum[tid * 2 + 1], 1.f);
        atomicAdd(acc, -logf(s1) - logf(s2));
    }
}

__global__ void zero_acc(float* acc) { if (threadIdx.x < 2) acc[threadIdx.x] = 0.f; }

__global__ void finalize(const float* __restrict__ acc, float* __restrict__ out)
{
    out[0] = acc[0] * (1.f / ((float)B_LAB * (float)CDIM));
    out[1] = acc[1] * (1.f / (float)B_LAB);
}

// ---------------------------------------------------------------------------
extern "C" void kernel_launch(void* const* d_in, const int* in_sizes, int n_in,
                              void* d_out, int out_size, void* d_ws, size_t ws_size,
                              hipStream_t stream)
{
    const float* x    = (const float*)d_in[0];
    const int*   y    = (const int*)  d_in[1];
    const float* xu   = (const float*)d_in[2];
    const int*   aidx = (const int*)  d_in[3];
    // d_in[4] assoc_mask (all ones) - unused
    const int*   nidx = (const int*)  d_in[5];
    // d_in[6] neg_assoc_mask (all ones) - unused
    const float* W1 = (const float*)d_in[7];
    const float* b1 = (const float*)d_in[8];
    const float* W2 = (const float*)d_in[9];
    const float* b2 = (const float*)d_in[10];
    const float* W3 = (const float*)d_in[11];
    const float* b3 = (const float*)d_in[12];

    float* ws  = (float*)d_ws;
    float* H1  = ws;                                  // [2048, 512]
    float* H2  = H1 + (size_t)B_TOT * H1DIM;          // [2048, 128]
    float* OUT = H2 + (size_t)B_TOT * H2DIM;          // [2048, 1024]
    float* acc = OUT + (size_t)B_TOT * CDIM;          // [2]
    float* out = (float*)d_out;

    zero_acc<<<1, 64, 0, stream>>>(acc);

    gemm_xwt<1><<<dim3(H1DIM / 64, B_TOT / 64), 256, 0, stream>>>(
        x, xu, B_LAB, W1, b1, H1, B_TOT, H1DIM, DDIM);
    gemm_xwt<1><<<dim3(H2DIM / 64, B_TOT / 64), 256, 0, stream>>>(
        H1, H1, B_TOT, W2, b2, H2, B_TOT, H2DIM, H1DIM);
    gemm_xwt<0><<<dim3(CDIM / 64, B_TOT / 64), 256, 0, stream>>>(
        H2, H2, B_TOT, W3, b3, OUT, B_TOT, CDIM, H2DIM);

    ce_kernel<<<1024, 256, 0, stream>>>(OUT, y, acc);
    sem_loss_kernel<<<B_TOT / 8, 256, 0, stream>>>(OUT, aidx, nidx, acc + 1);
    finalize<<<1, 1, 0, stream>>>(acc, out);
}

// Round 2
// 154.683 us; speedup vs baseline: 7.2890x; 7.2890x over previous
//
#include <hip/hip_runtime.h>
#include <math.h>

// Problem dims (fixed by setup_inputs)
#define B_LAB 1024
#define B_TOT 2048
#define CDIM  1024
#define DDIM  784
#define H1DIM 512
#define H2DIM 128
#define ADIM  32
#define NADIM 64

// Workspace layout (float offsets). Total = 3,407,874 floats = 13,631,496 B
// (exactly round-1's footprint, which fit).
//   [WS_H1 , +1,048,576) : H1 fp32 (gemm1->gemm2); later Mab+Mnb bf16 (4 MB)
//   [WS_H2 , +  262,144) : H2 fp32 (gemm2->gemm3); later rows1/rows2 (4096 f)
//   [WS_C  , +2,097,152) : cntA+cntN fp32 (8 MB); later LPb+L1Pb bf16 (8 MB)
//   [WS_ACC, +2)         : ce accumulator
#define WS_H1   0
#define WS_H2   1048576
#define WS_C    1310720
#define WS_ACC  3407872

typedef __attribute__((ext_vector_type(8))) __bf16 bf16x8;
typedef __attribute__((ext_vector_type(4))) float f32x4;

__device__ __forceinline__ unsigned short f2bf(float f) {
    unsigned int u = __builtin_bit_cast(unsigned int, f);
    u = (u + 0x7fff + ((u >> 16) & 1)) >> 16;   // RNE
    return (unsigned short)u;
}

__device__ __forceinline__ void gload_lds16(const void* g, void* l) {
    __builtin_amdgcn_global_load_lds(
        (const __attribute__((address_space(1))) unsigned int*)g,
        (__attribute__((address_space(3))) unsigned int*)l, 16, 0, 0);
}

// ---------------------------------------------------------------------------
// fp32 GEMM for MLP layers 1-2: out = relu(A @ W^T + b). 64x64 tile, BK=16.
// ---------------------------------------------------------------------------
template <int RELU>
__global__ __launch_bounds__(256) void gemm_xwt(
    const float* __restrict__ A0, const float* __restrict__ A1, int rows0,
    const float* __restrict__ W, const float* __restrict__ bias,
    float* __restrict__ out, int M, int N, int K)
{
    __shared__ float As[16][68];
    __shared__ float Ws[16][68];

    const int tid = threadIdx.x;
    const int tx = tid & 15, ty = tid >> 4;
    const int m0 = blockIdx.y * 64, n0 = blockIdx.x * 64;

    float acc[4][4] = {};

    for (int k0 = 0; k0 < K; k0 += 16) {
        #pragma unroll
        for (int l = 0; l < 4; ++l) {
            int linear = tid + l * 256;
            int kk = linear & 15, mm = linear >> 4;
            int m = m0 + mm;
            const float* srcA = (m < rows0) ? (A0 + (size_t)m * K)
                                            : (A1 + (size_t)(m - rows0) * K);
            As[kk][mm] = srcA[k0 + kk];
            Ws[kk][mm] = W[(size_t)(n0 + mm) * K + (k0 + kk)];
        }
        __syncthreads();
        #pragma unroll
        for (int kk = 0; kk < 16; ++kk) {
            float a[4], w[4];
            #pragma unroll
            for (int i = 0; i < 4; ++i) a[i] = As[kk][ty * 4 + i];
            #pragma unroll
            for (int j = 0; j < 4; ++j) w[j] = Ws[kk][tx * 4 + j];
            #pragma unroll
            for (int i = 0; i < 4; ++i)
                #pragma unroll
                for (int j = 0; j < 4; ++j)
                    acc[i][j] = fmaf(a[i], w[j], acc[i][j]);
        }
        __syncthreads();
    }

    #pragma unroll
    for (int i = 0; i < 4; ++i) {
        int m = m0 + ty * 4 + i;
        #pragma unroll
        for (int j = 0; j < 4; ++j) {
            int n = n0 + tx * 4 + j;
            float v = acc[i][j] + bias[n];
            if (RELU) v = fmaxf(v, 0.f);
            out[(size_t)m * N + n] = v;
        }
    }
}

// ---------------------------------------------------------------------------
// GEMM3 fused: z = H2 @ W3^T + b3; CE partial sum (labeled rows) -> atomic;
// lp/l1p -> bf16 arrays. K=128, N=1024, M=2048. 64x64 tile.
// ---------------------------------------------------------------------------
__global__ __launch_bounds__(256) void gemm3_fused(
    const float* __restrict__ A, const float* __restrict__ W,
    const float* __restrict__ bias, const int* __restrict__ y,
    unsigned short* __restrict__ LPb, unsigned short* __restrict__ L1Pb,
    float* __restrict__ ce_acc)
{
    __shared__ float As[16][68];
    __shared__ float Ws[16][68];
    __shared__ float part[4];

    const int tid = threadIdx.x;
    const int tx = tid & 15, ty = tid >> 4;
    const int m0 = blockIdx.y * 64, n0 = blockIdx.x * 64;

    float acc[4][4] = {};

    for (int k0 = 0; k0 < H2DIM; k0 += 16) {
        #pragma unroll
        for (int l = 0; l < 4; ++l) {
            int linear = tid + l * 256;
            int kk = linear & 15, mm = linear >> 4;
            As[kk][mm] = A[(size_t)(m0 + mm) * H2DIM + (k0 + kk)];
            Ws[kk][mm] = W[(size_t)(n0 + mm) * H2DIM + (k0 + kk)];
        }
        __syncthreads();
        #pragma unroll
        for (int kk = 0; kk < 16; ++kk) {
            float a[4], w[4];
            #pragma unroll
            for (int i = 0; i < 4; ++i) a[i] = As[kk][ty * 4 + i];
            #pragma unroll
            for (int j = 0; j < 4; ++j) w[j] = Ws[kk][tx * 4 + j];
            #pragma unroll
            for (int i = 0; i < 4; ++i)
                #pragma unroll
                for (int j = 0; j < 4; ++j)
                    acc[i][j] = fmaf(a[i], w[j], acc[i][j]);
        }
        __syncthreads();
    }

    const bool lab = (m0 < B_LAB);
    float ce_local = 0.f;
    #pragma unroll
    for (int i = 0; i < 4; ++i) {
        int m = m0 + ty * 4 + i;
        int tgt = lab ? y[m] : -1;
        #pragma unroll
        for (int j = 0; j < 4; ++j) {
            int n = n0 + tx * 4 + j;
            float z = acc[i][j] + bias[n];
            float p = 1.f / (1.f + expf(-z));
            LPb[m * CDIM + n]  = f2bf(logf(p + 1e-9f));
            L1Pb[m * CDIM + n] = f2bf(logf(1.f - p + 1e-9f));
            if (lab) {
                float sp = fmaxf(z, 0.f) + log1pf(expf(-fabsf(z)));
                if (n == tgt) sp -= z;
                ce_local += sp;
            }
        }
    }
    if (lab) {
        for (int off = 32; off; off >>= 1) ce_local += __shfl_down(ce_local, off);
        if ((tid & 63) == 0) part[tid >> 6] = ce_local;
        __syncthreads();
        if (tid == 0)
            atomicAdd(ce_acc, part[0] + part[1] + part[2] + part[3]);
    }
}

// ---------------------------------------------------------------------------
// Semantic-loss GEMM: S = A(bf16)[2048,1024] @ B(bf16)[1024,1024]^T,
// epilogue: rows[m] += sum_n exp(min(S[m,n],5)).  128x128 tile, BK=64,
// 4 waves (2x2 of 64x64), mfma_f32_16x16x32_bf16, XOR-swizzled LDS with
// pre-swizzled global source (global_load_lds dest must stay linear).
// blockIdx.z selects (LPb,Mab,rows1) vs (L1Pb,Mnb,rows2).
// ---------------------------------------------------------------------------
__global__ __launch_bounds__(256) void sem_gemm(
    const unsigned short* __restrict__ LPb, const unsigned short* __restrict__ L1Pb,
    const unsigned short* __restrict__ Mab, const unsigned short* __restrict__ Mnb,
    float* __restrict__ rows1, float* __restrict__ rows2)
{
    __shared__ __align__(16) char smem[32768];
    char* Asm = smem;
    char* Bsm = smem + 16384;

    const unsigned short* Ag = (blockIdx.z == 0) ? LPb : L1Pb;
    const unsigned short* Bg = (blockIdx.z == 0) ? Mab : Mnb;
    float* rows = (blockIdx.z == 0) ? rows1 : rows2;

    const int tid  = threadIdx.x;
    const int lane = tid & 63;
    const int w    = tid >> 6;
    const int wr   = w >> 1, wc = w & 1;
    const int lr   = lane & 15, lg = lane >> 4;
    const int m00  = blockIdx.y * 128;
    const int n00  = blockIdx.x * 128;

    f32x4 acc[4][4] = {};

    for (int kt = 0; kt < CDIM / 64; ++kt) {
        const int k0 = kt * 64;
        // Stage 128x64 bf16 tiles. LDS dest linear (lane-contiguous 16B);
        // source address pre-swizzled so LDS[byte] = elem[byte ^ ((row&7)<<4)].
        #pragma unroll
        for (int l = 0; l < 4; ++l) {
            int d = (l * 256 + tid) << 4;              // linear LDS byte
            int e = d ^ (((d >> 7) & 7) << 4);         // swizzled element byte
            int row = d >> 7;                          // row bits unchanged
            int col = (e & 127) >> 1;                  // halfword col (mult of 8)
            gload_lds16(Ag + (size_t)(m00 + row) * CDIM + k0 + col, Asm + d);
            gload_lds16(Bg + (size_t)(n00 + row) * CDIM + k0 + col, Bsm + d);
        }
        __syncthreads();   // drains vmcnt (global_load_lds) + lgkm

        #pragma unroll
        for (int ks = 0; ks < 2; ++ks) {
            bf16x8 af[4], bfv[4];
            #pragma unroll
            for (int mi = 0; mi < 4; ++mi) {
                int r = wr * 64 + mi * 16 + lr;
                af[mi] = *(const bf16x8*)(Asm + r * 128 +
                          ((ks * 64 + lg * 16) ^ ((r & 7) << 4)));
            }
            #pragma unroll
            for (int ni = 0; ni < 4; ++ni) {
                int r = wc * 64 + ni * 16 + lr;
                bfv[ni] = *(const bf16x8*)(Bsm + r * 128 +
                          ((ks * 64 + lg * 16) ^ ((r & 7) << 4)));
            }
            #pragma unroll
            for (int mi = 0; mi < 4; ++mi)
                #pragma unroll
                for (int ni = 0; ni < 4; ++ni)
                    acc[mi][ni] = __builtin_amdgcn_mfma_f32_16x16x32_bf16(
                        af[mi], bfv[ni], acc[mi][ni], 0, 0, 0);
        }
        __syncthreads();
    }

    // Epilogue: per element exp(min(s,5)), reduce over n (4 ni in-register,
    // 16 lanes via shfl_xor), atomicAdd per m-row.
    // D mapping (m89-verified): col = lane&15, row = (lane>>4)*4 + reg.
    #pragma unroll
    for (int mi = 0; mi < 4; ++mi) {
        #pragma unroll
        for (int r = 0; r < 4; ++r) {
            float s = 0.f;
            #pragma unroll
            for (int ni = 0; ni < 4; ++ni)
                s += expf(fminf(acc[mi][ni][r], 5.f));
            s += __shfl_xor(s, 1);
            s += __shfl_xor(s, 2);
            s += __shfl_xor(s, 4);
            s += __shfl_xor(s, 8);
            if (lr == 0) {
                int m = m00 + wr * 64 + mi * 16 + lg * 4 + r;
                atomicAdd(&rows[m], s);
            }
        }
    }
}

// ---------------------------------------------------------------------------
// Small helpers
// ---------------------------------------------------------------------------
__global__ __launch_bounds__(256) void zero_f32(float* p, int n)
{
    int i = blockIdx.x * 256 + threadIdx.x;
    if (i < n) p[i] = 0.f;
}

__global__ __launch_bounds__(256) void scatter_counts(
    const int* __restrict__ aidx, const int* __restrict__ nidx,
    float* __restrict__ cnt)
{
    int idx = blockIdx.x * 256 + threadIdx.x;
    if (idx < CDIM * ADIM) {
        int i = idx >> 5;                       // class row
        atomicAdd(&cnt[i * CDIM + aidx[idx]], 1.f);
    } else if (idx < CDIM * ADIM + CDIM * NADIM) {
        int j = idx - CDIM * ADIM;
        int i = j >> 6;
        atomicAdd(&cnt[CDIM * CDIM + i * CDIM + nidx[j]], 1.f);
    }
}

__global__ __launch_bounds__(256) void cvt_counts(
    const float* __restrict__ cnt, unsigned short* __restrict__ outbf)
{
    int i = blockIdx.x * 256 + threadIdx.x;     // float4 index
    float4 v = ((const float4*)cnt)[i];
    ushort4 o;
    o.x = f2bf(v.x); o.y = f2bf(v.y); o.z = f2bf(v.z); o.w = f2bf(v.w);
    ((ushort4*)outbf)[i] = o;
}

__global__ __launch_bounds__(256) void final_kernel(
    const float* __restrict__ rows1, const float* __restrict__ rows2,
    const float* __restrict__ ce_acc, float* __restrict__ out)
{
    __shared__ float part[4];
    float s = 0.f;
    for (int i = threadIdx.x; i < B_TOT; i += 256)
        s += -logf(fminf(rows1[i], 1.f)) - logf(fminf(rows2[i], 1.f));
    for (int off = 32; off; off >>= 1) s += __shfl_down(s, off);
    if ((threadIdx.x & 63) == 0) part[threadIdx.x >> 6] = s;
    __syncthreads();
    if (threadIdx.x == 0) {
        out[1] = (part[0] + part[1] + part[2] + part[3]) * (1.f / (float)B_LAB);
        out[0] = ce_acc[0] * (1.f / ((float)B_LAB * (float)CDIM));
    }
}

// ---------------------------------------------------------------------------
extern "C" void kernel_launch(void* const* d_in, const int* in_sizes, int n_in,
                              void* d_out, int out_size, void* d_ws, size_t ws_size,
                              hipStream_t stream)
{
    const float* x    = (const float*)d_in[0];
    const int*   y    = (const int*)  d_in[1];
    const float* xu   = (const float*)d_in[2];
    const int*   aidx = (const int*)  d_in[3];
    const int*   nidx = (const int*)  d_in[5];
    const float* W1 = (const float*)d_in[7];
    const float* b1 = (const float*)d_in[8];
    const float* W2 = (const float*)d_in[9];
    const float* b2 = (const float*)d_in[10];
    const float* W3 = (const float*)d_in[11];
    const float* b3 = (const float*)d_in[12];

    float* ws   = (float*)d_ws;
    float* H1   = ws + WS_H1;
    float* H2   = ws + WS_H2;
    float* CNT  = ws + WS_C;                      // cntA(1M) + cntN(1M) fp32
    float* ACC  = ws + WS_ACC;                    // [0]=ce sum
    float* ROWS = ws + WS_H2;                     // rows1(2048)+rows2(2048), after H2 dies
    unsigned short* Mab  = (unsigned short*)(ws + WS_H1);           // 1M hw
    unsigned short* Mnb  = Mab + CDIM * CDIM;                       // 1M hw
    unsigned short* LPb  = (unsigned short*)(ws + WS_C);            // 2M hw
    unsigned short* L1Pb = LPb + (size_t)B_TOT * CDIM;              // 2M hw
    float* out = (float*)d_out;

    // 1) zero count region + ce accumulator (contiguous)
    zero_f32<<<(2 * CDIM * CDIM + 2 + 255) / 256, 256, 0, stream>>>(CNT, 2 * CDIM * CDIM + 2);
    // 2) build count matrices
    scatter_counts<<<(CDIM * (ADIM + NADIM)) / 256, 256, 0, stream>>>(aidx, nidx, CNT);
    // 3) MLP layers 1-2 (fp32)
    gemm_xwt<1><<<dim3(H1DIM / 64, B_TOT / 64), 256, 0, stream>>>(
        x, xu, B_LAB, W1, b1, H1, B_TOT, H1DIM, DDIM);
    gemm_xwt<1><<<dim3(H2DIM / 64, B_TOT / 64), 256, 0, stream>>>(
        H1, H1, B_TOT, W2, b2, H2, B_TOT, H2DIM, H1DIM);
    // 4) counts -> bf16 (into dead H1 region)
    cvt_counts<<<(2 * CDIM * CDIM / 4) / 256, 256, 0, stream>>>(CNT, Mab);
    // 5) layer 3 + CE + logprobs->bf16 (LPb overwrites dead count region)
    gemm3_fused<<<dim3(CDIM / 64, B_TOT / 64), 256, 0, stream>>>(
        H2, W3, b3, y, LPb, L1Pb, ACC);
    // 6) zero row accumulators (in dead H2 region)
    zero_f32<<<16, 256, 0, stream>>>(ROWS, 2 * B_TOT);
    // 7) semantic GEMM, both branches in one dispatch (z)
    sem_gemm<<<dim3(CDIM / 128, B_TOT / 128, 2), 256, 0, stream>>>(
        LPb, L1Pb, Mab, Mnb, ROWS, ROWS + B_TOT);
    // 8) finalize both outputs
    final_kernel<<<1, 256, 0, stream>>>(ROWS, ROWS + B_TOT, ACC, out);
}

// Round 3
// 85.258 us; speedup vs baseline: 13.2246x; 1.8143x over previous
//
#include <hip/hip_runtime.h>
#include <math.h>

// Problem dims (fixed by setup_inputs)
#define B_LAB 1024
#define B_TOT 2048
#define CDIM  1024
#define DDIM  784
#define DPAD  832      // 784 padded to multiple of 64
#define H1DIM 512
#define H2DIM 128

typedef __attribute__((ext_vector_type(8))) __bf16 bf16x8;
typedef __attribute__((ext_vector_type(4))) float f32x4;
typedef __attribute__((ext_vector_type(8))) unsigned short ushort8;

// ---------------------------------------------------------------------------
// Workspace layout (byte offsets). Peak = 13,516,808 B <= round-2's proven
// 13,631,496 B footprint.
//  [0       , 8,388,608) : phase A: Xb(3.4M) + W1b(0.85M) + H1b(2.1M)  (all
//                          dead after layer2) -> phase B: LPb(4M)+L1Pb(4M)
//  [8,388,608 ,12,582,912): Mab(2M) + Mnb(2M) bf16 count matrices
//  [12,582,912,13,500,416): W2b + W3b + H2b  bf16
//  [13,500,416,13,516,808): rows1(2048 f32) + rows2(2048) + ce_acc(2)
// ---------------------------------------------------------------------------
#define OFF_XB    0u
#define OFF_W1B   3407872u
#define OFF_H1B   4259840u
#define OFF_LPB   0u
#define OFF_L1PB  4194304u
#define OFF_MAB   8388608u
#define OFF_MNB   10485760u
#define OFF_W2B   12582912u
#define OFF_W3B   12713984u
#define OFF_H2B   12976128u
#define OFF_ROWS  13500416u

__device__ __forceinline__ unsigned short f2bf(float f) {
    unsigned int u = __builtin_bit_cast(unsigned int, f);
    u = (u + 0x7fff + ((u >> 16) & 1)) >> 16;   // RNE
    return (unsigned short)u;
}

__device__ __forceinline__ void gload_lds16(const void* g, void* l) {
    __builtin_amdgcn_global_load_lds(
        (const __attribute__((address_space(1))) unsigned int*)g,
        (__attribute__((address_space(3))) unsigned int*)l, 16, 0, 0);
}

// ---------------------------------------------------------------------------
// Per-class association count matrices, built in LDS, written as bf16.
// Mab[i][c] = #{k : assoc_idx[i,k]==c}, Mnb likewise for neg_assoc.
// ---------------------------------------------------------------------------
__global__ __launch_bounds__(256) void build_counts(
    const int* __restrict__ aidx, const int* __restrict__ nidx,
    unsigned short* __restrict__ Mab, unsigned short* __restrict__ Mnb)
{
    __shared__ int cnt[2 * CDIM];
    const int i = blockIdx.x, tid = threadIdx.x;
    for (int j = tid; j < 2 * CDIM; j += 256) cnt[j] = 0;
    __syncthreads();
    if (tid < 32)       atomicAdd(&cnt[aidx[i * 32 + tid]], 1);
    else if (tid < 96)  atomicAdd(&cnt[CDIM + nidx[i * 64 + (tid - 32)]], 1);
    __syncthreads();
    for (int j = tid; j < CDIM; j += 256) {
        Mab[(size_t)i * CDIM + j] = f2bf((float)cnt[j]);
        Mnb[(size_t)i * CDIM + j] = f2bf((float)cnt[CDIM + j]);
    }
}

// ---------------------------------------------------------------------------
// fp32 -> bf16 convert with K -> Kp zero-padding. grid = (ceil(Kp/8/256), rows)
// ---------------------------------------------------------------------------
__global__ __launch_bounds__(256) void cvt_pad(
    const float* __restrict__ src, unsigned short* __restrict__ dst,
    int K, int Kp)
{
    const int c   = (blockIdx.x * 256 + threadIdx.x) * 8;
    const int row = blockIdx.y;
    if (c >= Kp) return;
    ushort8 o = {};
    if (c < K) {
        const float4* s = (const float4*)(src + (size_t)row * K + c);
        float4 a = s[0], b = s[1];
        o[0] = f2bf(a.x); o[1] = f2bf(a.y); o[2] = f2bf(a.z); o[3] = f2bf(a.w);
        o[4] = f2bf(b.x); o[5] = f2bf(b.y); o[6] = f2bf(b.z); o[7] = f2bf(b.w);
    }
    *(ushort8*)(dst + (size_t)row * Kp + c) = o;
}

// ---------------------------------------------------------------------------
// bf16 MFMA GEMM: out = act(A[M,K] @ W[N,K]^T + bias), out bf16.
// 64x64 tile, BK=64, 4 waves (2x2 of 32x32), 2-phase double-buffered LDS,
// XOR-swizzled layout with pre-swizzled global_load_lds source (layout
// verbatim from the round-2-verified sem_gemm).
// ---------------------------------------------------------------------------
template <int RELU>
__global__ __launch_bounds__(256) void mfma_gemm(
    const unsigned short* __restrict__ A, const unsigned short* __restrict__ W,
    const float* __restrict__ bias, unsigned short* __restrict__ out,
    int M, int N, int K)
{
    __shared__ __align__(16) char smem[2][16384];

    const int tid  = threadIdx.x;
    const int lane = tid & 63;
    const int w    = tid >> 6;
    const int wr   = w >> 1, wc = w & 1;
    const int lr   = lane & 15, lg = lane >> 4;
    const int m0   = blockIdx.y * 64;
    const int n0   = blockIdx.x * 64;
    const int NT   = K >> 6;

    f32x4 acc[2][2] = {};

    auto stage = [&](int b, int kt) {
        char* As = smem[b];
        char* Bs = smem[b] + 8192;
        #pragma unroll
        for (int l = 0; l < 2; ++l) {
            int d   = (l * 256 + tid) << 4;          // linear LDS byte
            int row = d >> 7;
            int e   = d ^ ((row & 7) << 4);          // swizzled element byte
            int col = (e & 127) >> 1;                // halfword col
            gload_lds16(A + (size_t)(m0 + row) * K + kt * 64 + col, As + d);
            gload_lds16(W + (size_t)(n0 + row) * K + kt * 64 + col, Bs + d);
        }
    };

    stage(0, 0);
    __syncthreads();

    int cur = 0;
    for (int kt = 0; kt < NT; ++kt) {
        if (kt + 1 < NT) stage(cur ^ 1, kt + 1);
        char* As = smem[cur];
        char* Bs = smem[cur] + 8192;
        #pragma unroll
        for (int ks = 0; ks < 2; ++ks) {
            bf16x8 af[2], bfv[2];
            #pragma unroll
            for (int mi = 0; mi < 2; ++mi) {
                int r = wr * 32 + mi * 16 + lr;
                af[mi] = *(const bf16x8*)(As + r * 128 +
                          ((ks * 64 + lg * 16) ^ ((r & 7) << 4)));
            }
            #pragma unroll
            for (int ni = 0; ni < 2; ++ni) {
                int r = wc * 32 + ni * 16 + lr;
                bfv[ni] = *(const bf16x8*)(Bs + r * 128 +
                          ((ks * 64 + lg * 16) ^ ((r & 7) << 4)));
            }
            #pragma unroll
            for (int mi = 0; mi < 2; ++mi)
                #pragma unroll
                for (int ni = 0; ni < 2; ++ni)
                    acc[mi][ni] = __builtin_amdgcn_mfma_f32_16x16x32_bf16(
                        af[mi], bfv[ni], acc[mi][ni], 0, 0, 0);
        }
        __syncthreads();   // drains vmcnt (next-tile stage) + lgkm, barrier
        cur ^= 1;
    }

    // D mapping: col(n) = lane&15, row(m) = (lane>>4)*4 + reg
    #pragma unroll
    for (int mi = 0; mi < 2; ++mi)
        #pragma unroll
        for (int r = 0; r < 4; ++r) {
            int m = m0 + wr * 32 + mi * 16 + lg * 4 + r;
            #pragma unroll
            for (int ni = 0; ni < 2; ++ni) {
                int n = n0 + wc * 32 + ni * 16 + lr;
                float v = acc[mi][ni][r] + bias[n];
                if (RELU) v = fmaxf(v, 0.f);
                out[(size_t)m * N + n] = f2bf(v);
            }
        }
}

// ---------------------------------------------------------------------------
// Layer 3 fused: z = H2b @ W3b^T + b3 (bf16 MFMA, K=128); epilogue computes
// CE partial sums (labeled rows) and logp / log1mp in bf16.
// ---------------------------------------------------------------------------
__global__ __launch_bounds__(256) void gemm3_fused(
    const unsigned short* __restrict__ A, const unsigned short* __restrict__ W,
    const float* __restrict__ bias, const int* __restrict__ y,
    unsigned short* __restrict__ LPb, unsigned short* __restrict__ L1Pb,
    float* __restrict__ ce_acc)
{
    __shared__ __align__(16) char smem[2][16384];
    __shared__ float part[4];

    const int tid  = threadIdx.x;
    const int lane = tid & 63;
    const int w    = tid >> 6;
    const int wr   = w >> 1, wc = w & 1;
    const int lr   = lane & 15, lg = lane >> 4;
    const int m0   = blockIdx.y * 64;
    const int n0   = blockIdx.x * 64;
    const int NT   = H2DIM >> 6;   // 2

    f32x4 acc[2][2] = {};

    auto stage = [&](int b, int kt) {
        char* As = smem[b];
        char* Bs = smem[b] + 8192;
        #pragma unroll
        for (int l = 0; l < 2; ++l) {
            int d   = (l * 256 + tid) << 4;
            int row = d >> 7;
            int e   = d ^ ((row & 7) << 4);
            int col = (e & 127) >> 1;
            gload_lds16(A + (size_t)(m0 + row) * H2DIM + kt * 64 + col, As + d);
            gload_lds16(W + (size_t)(n0 + row) * H2DIM + kt * 64 + col, Bs + d);
        }
    };

    stage(0, 0);
    __syncthreads();

    int cur = 0;
    for (int kt = 0; kt < NT; ++kt) {
        if (kt + 1 < NT) stage(cur ^ 1, kt + 1);
        char* As = smem[cur];
        char* Bs = smem[cur] + 8192;
        #pragma unroll
        for (int ks = 0; ks < 2; ++ks) {
            bf16x8 af[2], bfv[2];
            #pragma unroll
            for (int mi = 0; mi < 2; ++mi) {
                int r = wr * 32 + mi * 16 + lr;
                af[mi] = *(const bf16x8*)(As + r * 128 +
                          ((ks * 64 + lg * 16) ^ ((r & 7) << 4)));
            }
            #pragma unroll
            for (int ni = 0; ni < 2; ++ni) {
                int r = wc * 32 + ni * 16 + lr;
                bfv[ni] = *(const bf16x8*)(Bs + r * 128 +
                          ((ks * 64 + lg * 16) ^ ((r & 7) << 4)));
            }
            #pragma unroll
            for (int mi = 0; mi < 2; ++mi)
                #pragma unroll
                for (int ni = 0; ni < 2; ++ni)
                    acc[mi][ni] = __builtin_amdgcn_mfma_f32_16x16x32_bf16(
                        af[mi], bfv[ni], acc[mi][ni], 0, 0, 0);
        }
        __syncthreads();
        cur ^= 1;
    }

    const bool lab = (m0 < B_LAB);      // 1024 % 64 == 0: uniform per block
    float ce_local = 0.f;
    #pragma unroll
    for (int mi = 0; mi < 2; ++mi)
        #pragma unroll
        for (int r = 0; r < 4; ++r) {
            int m = m0 + wr * 32 + mi * 16 + lg * 4 + r;
            int tgt = lab ? y[m] : -1;
            #pragma unroll
            for (int ni = 0; ni < 2; ++ni) {
                int n = n0 + wc * 32 + ni * 16 + lr;
                float z = acc[mi][ni][r] + bias[n];
                float p = 1.f / (1.f + expf(-z));
                LPb[(size_t)m * CDIM + n]  = f2bf(logf(p + 1e-9f));
                L1Pb[(size_t)m * CDIM + n] = f2bf(logf(1.f - p + 1e-9f));
                if (lab) {
                    float sp = fmaxf(z, 0.f) + log1pf(expf(-fabsf(z)));
                    if (n == tgt) sp -= z;
                    ce_local += sp;
                }
            }
        }
    if (lab) {
        for (int off = 32; off; off >>= 1) ce_local += __shfl_down(ce_local, off);
        if ((tid & 63) == 0) part[tid >> 6] = ce_local;
        __syncthreads();
        if (tid == 0)
            atomicAdd(ce_acc, part[0] + part[1] + part[2] + part[3]);
    }
}

// ---------------------------------------------------------------------------
// Semantic-loss GEMM (unchanged from round 2, verified):
// S = A(bf16)[2048,1024] @ B(bf16)[1024,1024]^T, rows[m] += sum_n exp(min(S,5))
// ---------------------------------------------------------------------------
__global__ __launch_bounds__(256) void sem_gemm(
    const unsigned short* __restrict__ LPb, const unsigned short* __restrict__ L1Pb,
    const unsigned short* __restrict__ Mab, const unsigned short* __restrict__ Mnb,
    float* __restrict__ rows1, float* __restrict__ rows2)
{
    __shared__ __align__(16) char smem[32768];
    char* Asm = smem;
    char* Bsm = smem + 16384;

    const unsigned short* Ag = (blockIdx.z == 0) ? LPb : L1Pb;
    const unsigned short* Bg = (blockIdx.z == 0) ? Mab : Mnb;
    float* rows = (blockIdx.z == 0) ? rows1 : rows2;

    const int tid  = threadIdx.x;
    const int lane = tid & 63;
    const int w    = tid >> 6;
    const int wr   = w >> 1, wc = w & 1;
    const int lr   = lane & 15, lg = lane >> 4;
    const int m00  = blockIdx.y * 128;
    const int n00  = blockIdx.x * 128;

    f32x4 acc[4][4] = {};

    for (int kt = 0; kt < CDIM / 64; ++kt) {
        const int k0 = kt * 64;
        #pragma unroll
        for (int l = 0; l < 4; ++l) {
            int d = (l * 256 + tid) << 4;
            int e = d ^ (((d >> 7) & 7) << 4);
            int row = d >> 7;
            int col = (e & 127) >> 1;
            gload_lds16(Ag + (size_t)(m00 + row) * CDIM + k0 + col, Asm + d);
            gload_lds16(Bg + (size_t)(n00 + row) * CDIM + k0 + col, Bsm + d);
        }
        __syncthreads();

        #pragma unroll
        for (int ks = 0; ks < 2; ++ks) {
            bf16x8 af[4], bfv[4];
            #pragma unroll
            for (int mi = 0; mi < 4; ++mi) {
                int r = wr * 64 + mi * 16 + lr;
                af[mi] = *(const bf16x8*)(Asm + r * 128 +
                          ((ks * 64 + lg * 16) ^ ((r & 7) << 4)));
            }
            #pragma unroll
            for (int ni = 0; ni < 4; ++ni) {
                int r = wc * 64 + ni * 16 + lr;
                bfv[ni] = *(const bf16x8*)(Bsm + r * 128 +
                          ((ks * 64 + lg * 16) ^ ((r & 7) << 4)));
            }
            #pragma unroll
            for (int mi = 0; mi < 4; ++mi)
                #pragma unroll
                for (int ni = 0; ni < 4; ++ni)
                    acc[mi][ni] = __builtin_amdgcn_mfma_f32_16x16x32_bf16(
                        af[mi], bfv[ni], acc[mi][ni], 0, 0, 0);
        }
        __syncthreads();
    }

    #pragma unroll
    for (int mi = 0; mi < 4; ++mi) {
        #pragma unroll
        for (int r = 0; r < 4; ++r) {
            float s = 0.f;
            #pragma unroll
            for (int ni = 0; ni < 4; ++ni)
                s += expf(fminf(acc[mi][ni][r], 5.f));
            s += __shfl_xor(s, 1);
            s += __shfl_xor(s, 2);
            s += __shfl_xor(s, 4);
            s += __shfl_xor(s, 8);
            if (lr == 0) {
                int m = m00 + wr * 64 + mi * 16 + lg * 4 + r;
                atomicAdd(&rows[m], s);
            }
        }
    }
}

// ---------------------------------------------------------------------------
__global__ __launch_bounds__(256) void zero_f32(float* p, int n)
{
    int i = blockIdx.x * 256 + threadIdx.x;
    if (i < n) p[i] = 0.f;
}

__global__ __launch_bounds__(256) void final_kernel(
    const float* __restrict__ rows1, const float* __restrict__ rows2,
    const float* __restrict__ ce_acc, float* __restrict__ out)
{
    __shared__ float part[4];
    float s = 0.f;
    for (int i = threadIdx.x; i < B_TOT; i += 256)
        s += -logf(fminf(rows1[i], 1.f)) - logf(fminf(rows2[i], 1.f));
    for (int off = 32; off; off >>= 1) s += __shfl_down(s, off);
    if ((threadIdx.x & 63) == 0) part[threadIdx.x >> 6] = s;
    __syncthreads();
    if (threadIdx.x == 0) {
        out[1] = (part[0] + part[1] + part[2] + part[3]) * (1.f / (float)B_LAB);
        out[0] = ce_acc[0] * (1.f / ((float)B_LAB * (float)CDIM));
    }
}

// ---------------------------------------------------------------------------
extern "C" void kernel_launch(void* const* d_in, const int* in_sizes, int n_in,
                              void* d_out, int out_size, void* d_ws, size_t ws_size,
                              hipStream_t stream)
{
    const float* x    = (const float*)d_in[0];
    const int*   y    = (const int*)  d_in[1];
    const float* xu   = (const float*)d_in[2];
    const int*   aidx = (const int*)  d_in[3];
    const int*   nidx = (const int*)  d_in[5];
    const float* W1 = (const float*)d_in[7];
    const float* b1 = (const float*)d_in[8];
    const float* W2 = (const float*)d_in[9];
    const float* b2 = (const float*)d_in[10];
    const float* W3 = (const float*)d_in[11];
    const float* b3 = (const float*)d_in[12];

    char* ws = (char*)d_ws;
    unsigned short* XB   = (unsigned short*)(ws + OFF_XB);
    unsigned short* W1B  = (unsigned short*)(ws + OFF_W1B);
    unsigned short* H1B  = (unsigned short*)(ws + OFF_H1B);
    unsigned short* LPb  = (unsigned short*)(ws + OFF_LPB);
    unsigned short* L1Pb = (unsigned short*)(ws + OFF_L1PB);
    unsigned short* MAB  = (unsigned short*)(ws + OFF_MAB);
    unsigned short* MNB  = (unsigned short*)(ws + OFF_MNB);
    unsigned short* W2B  = (unsigned short*)(ws + OFF_W2B);
    unsigned short* W3B  = (unsigned short*)(ws + OFF_W3B);
    unsigned short* H2B  = (unsigned short*)(ws + OFF_H2B);
    float* ROWS = (float*)(ws + OFF_ROWS);
    float* ACC  = ROWS + 2 * B_TOT;
    float* out  = (float*)d_out;

    // count matrices + conversions + accumulator zeroing
    build_counts<<<CDIM, 256, 0, stream>>>(aidx, nidx, MAB, MNB);
    cvt_pad<<<dim3(1, B_LAB), 256, 0, stream>>>(x,  XB, DDIM, DPAD);
    cvt_pad<<<dim3(1, B_LAB), 256, 0, stream>>>(xu, XB + (size_t)B_LAB * DPAD, DDIM, DPAD);
    cvt_pad<<<dim3(1, H1DIM), 256, 0, stream>>>(W1, W1B, DDIM, DPAD);
    cvt_pad<<<dim3(1, H2DIM), 256, 0, stream>>>(W2, W2B, H1DIM, H1DIM);
    cvt_pad<<<dim3(1, CDIM),  256, 0, stream>>>(W3, W3B, H2DIM, H2DIM);
    zero_f32<<<(2 * B_TOT + 2 + 255) / 256, 256, 0, stream>>>(ROWS, 2 * B_TOT + 2);

    // MLP on matrix cores
    mfma_gemm<1><<<dim3(H1DIM / 64, B_TOT / 64), 256, 0, stream>>>(
        XB, W1B, b1, H1B, B_TOT, H1DIM, DPAD);
    mfma_gemm<1><<<dim3(H2DIM / 64, B_TOT / 64), 256, 0, stream>>>(
        H1B, W2B, b2, H2B, B_TOT, H2DIM, H1DIM);
    gemm3_fused<<<dim3(CDIM / 64, B_TOT / 64), 256, 0, stream>>>(
        H2B, W3B, b3, y, LPb, L1Pb, ACC);

    // semantic loss GEMM (both branches via blockIdx.z)
    sem_gemm<<<dim3(CDIM / 128, B_TOT / 128, 2), 256, 0, stream>>>(
        LPb, L1Pb, MAB, MNB, ROWS, ROWS + B_TOT);
    final_kernel<<<1, 256, 0, stream>>>(ROWS, ROWS + B_TOT, ACC, out);
}

// Round 4
// 65.993 us; speedup vs baseline: 17.0850x; 1.2919x over previous
//
#include <hip/hip_runtime.h>
#include <math.h>

// Problem dims (fixed by setup_inputs)
#define B_LAB 1024
#define B_TOT 2048
#define CDIM  1024
#define DDIM  784
#define DPAD  832      // 784 padded to multiple of 64
#define H1DIM 512
#define H2DIM 128

typedef __attribute__((ext_vector_type(8))) __bf16 bf16x8;
typedef __attribute__((ext_vector_type(4))) float f32x4;
typedef __attribute__((ext_vector_type(8))) unsigned short ushort8;

// ---------------------------------------------------------------------------
// Workspace layout (byte offsets). Peak = 13,516,808 B (round-3 proven).
//  [0       , 8,388,608) : phase A: Xb(3.4M) + W1b(0.85M) + H1b(2.1M)
//                          -> phase B: LPb(4M)+L1Pb(4M)
//  [8,388,608 ,12,582,912): Mab(2M) + Mnb(2M) bf16 count matrices
//  [12,582,912,13,500,416): W2b + W3b + H2b  bf16
//  [13,500,416,13,516,808): rows1(2048 f32) + rows2(2048) + ce_acc(2)
// ---------------------------------------------------------------------------
#define OFF_XB    0u
#define OFF_W1B   3407872u
#define OFF_H1B   4259840u
#define OFF_LPB   0u
#define OFF_L1PB  4194304u
#define OFF_MAB   8388608u
#define OFF_MNB   10485760u
#define OFF_W2B   12582912u
#define OFF_W3B   12713984u
#define OFF_H2B   12976128u
#define OFF_ROWS  13500416u

__device__ __forceinline__ unsigned short f2bf(float f) {
    unsigned int u = __builtin_bit_cast(unsigned int, f);
    u = (u + 0x7fff + ((u >> 16) & 1)) >> 16;   // RNE
    return (unsigned short)u;
}

__device__ __forceinline__ void gload_lds16(const void* g, void* l) {
    __builtin_amdgcn_global_load_lds(
        (const __attribute__((address_space(1))) unsigned int*)g,
        (__attribute__((address_space(3))) unsigned int*)l, 16, 0, 0);
}

// ---------------------------------------------------------------------------
// Fused prep: one launch does count-matrices + all fp32->bf16 conversions +
// accumulator zeroing, selected by blockIdx.x range.
//   [0,1024)      : per-class count histograms -> Mab/Mnb bf16
//   [1024,1856)   : x (416 blks) / xu (416) -> XB with 784->832 pad
//   [1856,2064)   : W1 -> W1B (pad)
//   [2064,2096)   : W2 -> W2B
//   [2096,2160)   : W3 -> W3B
//   [2160,2163)   : zero rows1/rows2/ce_acc (4098 floats)
// Each conversion block handles 256 chunks of 8 elements.
// ---------------------------------------------------------------------------
__global__ __launch_bounds__(256) void prep(
    const int* __restrict__ aidx, const int* __restrict__ nidx,
    const float* __restrict__ x, const float* __restrict__ xu,
    const float* __restrict__ W1, const float* __restrict__ W2,
    const float* __restrict__ W3,
    unsigned short* __restrict__ Mab, unsigned short* __restrict__ Mnb,
    unsigned short* __restrict__ XB, unsigned short* __restrict__ W1B,
    unsigned short* __restrict__ W2B, unsigned short* __restrict__ W3B,
    float* __restrict__ zero_base)
{
    __shared__ int cnt[2 * CDIM];
    const int bid = blockIdx.x, tid = threadIdx.x;

    if (bid < 1024) {
        const int i = bid;
        for (int j = tid; j < 2 * CDIM; j += 256) cnt[j] = 0;
        __syncthreads();
        if (tid < 32)       atomicAdd(&cnt[aidx[i * 32 + tid]], 1);
        else if (tid < 96)  atomicAdd(&cnt[CDIM + nidx[i * 64 + (tid - 32)]], 1);
        __syncthreads();
        for (int j = tid; j < CDIM; j += 256) {
            Mab[(size_t)i * CDIM + j] = f2bf((float)cnt[j]);
            Mnb[(size_t)i * CDIM + j] = f2bf((float)cnt[CDIM + j]);
        }
        return;
    }
    if (bid < 2160) {
        const float* src; unsigned short* dst; int K, cpr, chunk;
        if (bid < 1856) {
            int b = bid - 1024;
            bool lab = (b < 416);
            src = lab ? x : xu;
            dst = XB + (lab ? (size_t)0 : (size_t)B_LAB * DPAD);
            K = DDIM; cpr = 104;
            chunk = (lab ? b : b - 416) * 256 + tid;
        } else if (bid < 2064) {
            src = W1; dst = W1B; K = DDIM; cpr = 104;
            chunk = (bid - 1856) * 256 + tid;
        } else if (bid < 2096) {
            src = W2; dst = W2B; K = H1DIM; cpr = 64;
            chunk = (bid - 2064) * 256 + tid;
        } else {
            src = W3; dst = W3B; K = H2DIM; cpr = 16;
            chunk = (bid - 2096) * 256 + tid;
        }
        int row = chunk / cpr;
        int col = (chunk - row * cpr) * 8;
        int Kp  = cpr * 8;
        ushort8 o = {};
        if (col < K) {   // 784 = 98*8: chunks are either fully data or fully pad
            const float4* s = (const float4*)(src + (size_t)row * K + col);
            float4 a = s[0], b4 = s[1];
            o[0] = f2bf(a.x);  o[1] = f2bf(a.y);  o[2] = f2bf(a.z);  o[3] = f2bf(a.w);
            o[4] = f2bf(b4.x); o[5] = f2bf(b4.y); o[6] = f2bf(b4.z); o[7] = f2bf(b4.w);
        }
        *(ushort8*)(dst + (size_t)row * Kp + col) = o;
        return;
    }
    // zero job: rows1+rows2+ce_acc = 2*B_TOT+2 floats
    int base = (bid - 2160) * 2048 + tid * 8;
    #pragma unroll
    for (int k = 0; k < 8; ++k) {
        int j = base + k;
        if (j < 2 * B_TOT + 2) zero_base[j] = 0.f;
    }
}

// ---------------------------------------------------------------------------
// bf16 MFMA GEMM: out = act(A[M,K] @ W[N,K]^T + bias), out bf16.
// 64x64 tile, BK=64, 4 waves, 2-phase double-buffered LDS, XOR-swizzled.
// ---------------------------------------------------------------------------
template <int RELU>
__global__ __launch_bounds__(256) void mfma_gemm(
    const unsigned short* __restrict__ A, const unsigned short* __restrict__ W,
    const float* __restrict__ bias, unsigned short* __restrict__ out,
    int M, int N, int K)
{
    __shared__ __align__(16) char smem[2][16384];

    const int tid  = threadIdx.x;
    const int lane = tid & 63;
    const int w    = tid >> 6;
    const int wr   = w >> 1, wc = w & 1;
    const int lr   = lane & 15, lg = lane >> 4;
    const int m0   = blockIdx.y * 64;
    const int n0   = blockIdx.x * 64;
    const int NT   = K >> 6;

    f32x4 acc[2][2] = {};

    auto stage = [&](int b, int kt) {
        char* As = smem[b];
        char* Bs = smem[b] + 8192;
        #pragma unroll
        for (int l = 0; l < 2; ++l) {
            int d   = (l * 256 + tid) << 4;
            int row = d >> 7;
            int e   = d ^ ((row & 7) << 4);
            int col = (e & 127) >> 1;
            gload_lds16(A + (size_t)(m0 + row) * K + kt * 64 + col, As + d);
            gload_lds16(W + (size_t)(n0 + row) * K + kt * 64 + col, Bs + d);
        }
    };

    stage(0, 0);
    __syncthreads();

    int cur = 0;
    for (int kt = 0; kt < NT; ++kt) {
        if (kt + 1 < NT) stage(cur ^ 1, kt + 1);
        char* As = smem[cur];
        char* Bs = smem[cur] + 8192;
        #pragma unroll
        for (int ks = 0; ks < 2; ++ks) {
            bf16x8 af[2], bfv[2];
            #pragma unroll
            for (int mi = 0; mi < 2; ++mi) {
                int r = wr * 32 + mi * 16 + lr;
                af[mi] = *(const bf16x8*)(As + r * 128 +
                          ((ks * 64 + lg * 16) ^ ((r & 7) << 4)));
            }
            #pragma unroll
            for (int ni = 0; ni < 2; ++ni) {
                int r = wc * 32 + ni * 16 + lr;
                bfv[ni] = *(const bf16x8*)(Bs + r * 128 +
                          ((ks * 64 + lg * 16) ^ ((r & 7) << 4)));
            }
            #pragma unroll
            for (int mi = 0; mi < 2; ++mi)
                #pragma unroll
                for (int ni = 0; ni < 2; ++ni)
                    acc[mi][ni] = __builtin_amdgcn_mfma_f32_16x16x32_bf16(
                        af[mi], bfv[ni], acc[mi][ni], 0, 0, 0);
        }
        __syncthreads();
        cur ^= 1;
    }

    #pragma unroll
    for (int mi = 0; mi < 2; ++mi)
        #pragma unroll
        for (int r = 0; r < 4; ++r) {
            int m = m0 + wr * 32 + mi * 16 + lg * 4 + r;
            #pragma unroll
            for (int ni = 0; ni < 2; ++ni) {
                int n = n0 + wc * 32 + ni * 16 + lr;
                float v = acc[mi][ni][r] + bias[n];
                if (RELU) v = fmaxf(v, 0.f);
                out[(size_t)m * N + n] = f2bf(v);
            }
        }
}

// ---------------------------------------------------------------------------
// Layer 3 fused: z = H2b @ W3b^T + b3 (bf16 MFMA, K=128); epilogue computes
// CE partial sums (labeled rows) and logp / log1mp in bf16.
// ---------------------------------------------------------------------------
__global__ __launch_bounds__(256) void gemm3_fused(
    const unsigned short* __restrict__ A, const unsigned short* __restrict__ W,
    const float* __restrict__ bias, const int* __restrict__ y,
    unsigned short* __restrict__ LPb, unsigned short* __restrict__ L1Pb,
    float* __restrict__ ce_acc)
{
    __shared__ __align__(16) char smem[2][16384];
    __shared__ float part[4];

    const int tid  = threadIdx.x;
    const int lane = tid & 63;
    const int w    = tid >> 6;
    const int wr   = w >> 1, wc = w & 1;
    const int lr   = lane & 15, lg = lane >> 4;
    const int m0   = blockIdx.y * 64;
    const int n0   = blockIdx.x * 64;
    const int NT   = H2DIM >> 6;   // 2

    f32x4 acc[2][2] = {};

    auto stage = [&](int b, int kt) {
        char* As = smem[b];
        char* Bs = smem[b] + 8192;
        #pragma unroll
        for (int l = 0; l < 2; ++l) {
            int d   = (l * 256 + tid) << 4;
            int row = d >> 7;
            int e   = d ^ ((row & 7) << 4);
            int col = (e & 127) >> 1;
            gload_lds16(A + (size_t)(m0 + row) * H2DIM + kt * 64 + col, As + d);
            gload_lds16(W + (size_t)(n0 + row) * H2DIM + kt * 64 + col, Bs + d);
        }
    };

    stage(0, 0);
    __syncthreads();

    int cur = 0;
    for (int kt = 0; kt < NT; ++kt) {
        if (kt + 1 < NT) stage(cur ^ 1, kt + 1);
        char* As = smem[cur];
        char* Bs = smem[cur] + 8192;
        #pragma unroll
        for (int ks = 0; ks < 2; ++ks) {
            bf16x8 af[2], bfv[2];
            #pragma unroll
            for (int mi = 0; mi < 2; ++mi) {
                int r = wr * 32 + mi * 16 + lr;
                af[mi] = *(const bf16x8*)(As + r * 128 +
                          ((ks * 64 + lg * 16) ^ ((r & 7) << 4)));
            }
            #pragma unroll
            for (int ni = 0; ni < 2; ++ni) {
                int r = wc * 32 + ni * 16 + lr;
                bfv[ni] = *(const bf16x8*)(Bs + r * 128 +
                          ((ks * 64 + lg * 16) ^ ((r & 7) << 4)));
            }
            #pragma unroll
            for (int mi = 0; mi < 2; ++mi)
                #pragma unroll
                for (int ni = 0; ni < 2; ++ni)
                    acc[mi][ni] = __builtin_amdgcn_mfma_f32_16x16x32_bf16(
                        af[mi], bfv[ni], acc[mi][ni], 0, 0, 0);
        }
        __syncthreads();
        cur ^= 1;
    }

    const bool lab = (m0 < B_LAB);
    float ce_local = 0.f;
    #pragma unroll
    for (int mi = 0; mi < 2; ++mi)
        #pragma unroll
        for (int r = 0; r < 4; ++r) {
            int m = m0 + wr * 32 + mi * 16 + lg * 4 + r;
            int tgt = lab ? y[m] : -1;
            #pragma unroll
            for (int ni = 0; ni < 2; ++ni) {
                int n = n0 + wc * 32 + ni * 16 + lr;
                float z = acc[mi][ni][r] + bias[n];
                float p = 1.f / (1.f + expf(-z));
                LPb[(size_t)m * CDIM + n]  = f2bf(logf(p + 1e-9f));
                L1Pb[(size_t)m * CDIM + n] = f2bf(logf(1.f - p + 1e-9f));
                if (lab) {
                    float sp = fmaxf(z, 0.f) + log1pf(expf(-fabsf(z)));
                    if (n == tgt) sp -= z;
                    ce_local += sp;
                }
            }
        }
    if (lab) {
        for (int off = 32; off; off >>= 1) ce_local += __shfl_down(ce_local, off);
        if ((tid & 63) == 0) part[tid >> 6] = ce_local;
        __syncthreads();
        if (tid == 0)
            atomicAdd(ce_acc, part[0] + part[1] + part[2] + part[3]);
    }
}

// ---------------------------------------------------------------------------
// Semantic-loss GEMM, now 2-phase double-buffered:
// S = A(bf16)[2048,1024] @ B(bf16)[1024,1024]^T, rows[m] += sum_n exp(min(S,5))
// 128x128 tile, BK=64, 4 waves (2x2 of 64x64). LDS 2 x 32 KB.
// ---------------------------------------------------------------------------
__global__ __launch_bounds__(256) void sem_gemm(
    const unsigned short* __restrict__ LPb, const unsigned short* __restrict__ L1Pb,
    const unsigned short* __restrict__ Mab, const unsigned short* __restrict__ Mnb,
    float* __restrict__ rows1, float* __restrict__ rows2)
{
    __shared__ __align__(16) char smem[2][32768];

    const unsigned short* Ag = (blockIdx.z == 0) ? LPb : L1Pb;
    const unsigned short* Bg = (blockIdx.z == 0) ? Mab : Mnb;
    float* rows = (blockIdx.z == 0) ? rows1 : rows2;

    const int tid  = threadIdx.x;
    const int lane = tid & 63;
    const int w    = tid >> 6;
    const int wr   = w >> 1, wc = w & 1;
    const int lr   = lane & 15, lg = lane >> 4;
    const int m00  = blockIdx.y * 128;
    const int n00  = blockIdx.x * 128;
    const int NT   = CDIM / 64;   // 16

    f32x4 acc[4][4] = {};

    auto stage = [&](int b, int kt) {
        char* Asm = smem[b];
        char* Bsm = smem[b] + 16384;
        const int k0 = kt * 64;
        #pragma unroll
        for (int l = 0; l < 4; ++l) {
            int d   = (l * 256 + tid) << 4;
            int row = d >> 7;
            int e   = d ^ ((row & 7) << 4);
            int col = (e & 127) >> 1;
            gload_lds16(Ag + (size_t)(m00 + row) * CDIM + k0 + col, Asm + d);
            gload_lds16(Bg + (size_t)(n00 + row) * CDIM + k0 + col, Bsm + d);
        }
    };

    stage(0, 0);
    __syncthreads();

    int cur = 0;
    for (int kt = 0; kt < NT; ++kt) {
        if (kt + 1 < NT) stage(cur ^ 1, kt + 1);
        char* Asm = smem[cur];
        char* Bsm = smem[cur] + 16384;
        #pragma unroll
        for (int ks = 0; ks < 2; ++ks) {
            bf16x8 af[4], bfv[4];
            #pragma unroll
            for (int mi = 0; mi < 4; ++mi) {
                int r = wr * 64 + mi * 16 + lr;
                af[mi] = *(const bf16x8*)(Asm + r * 128 +
                          ((ks * 64 + lg * 16) ^ ((r & 7) << 4)));
            }
            #pragma unroll
            for (int ni = 0; ni < 4; ++ni) {
                int r = wc * 64 + ni * 16 + lr;
                bfv[ni] = *(const bf16x8*)(Bsm + r * 128 +
                          ((ks * 64 + lg * 16) ^ ((r & 7) << 4)));
            }
            #pragma unroll
            for (int mi = 0; mi < 4; ++mi)
                #pragma unroll
                for (int ni = 0; ni < 4; ++ni)
                    acc[mi][ni] = __builtin_amdgcn_mfma_f32_16x16x32_bf16(
                        af[mi], bfv[ni], acc[mi][ni], 0, 0, 0);
        }
        __syncthreads();
        cur ^= 1;
    }

    // Epilogue: exp(min(s,5)), reduce over n, atomicAdd per m-row.
    #pragma unroll
    for (int mi = 0; mi < 4; ++mi) {
        #pragma unroll
        for (int r = 0; r < 4; ++r) {
            float s = 0.f;
            #pragma unroll
            for (int ni = 0; ni < 4; ++ni)
                s += expf(fminf(acc[mi][ni][r], 5.f));
            s += __shfl_xor(s, 1);
            s += __shfl_xor(s, 2);
            s += __shfl_xor(s, 4);
            s += __shfl_xor(s, 8);
            if (lr == 0) {
                int m = m00 + wr * 64 + mi * 16 + lg * 4 + r;
                atomicAdd(&rows[m], s);
            }
        }
    }
}

// ---------------------------------------------------------------------------
__global__ __launch_bounds__(256) void final_kernel(
    const float* __restrict__ rows1, const float* __restrict__ rows2,
    const float* __restrict__ ce_acc, float* __restrict__ out)
{
    __shared__ float part[4];
    float s = 0.f;
    for (int i = threadIdx.x; i < B_TOT; i += 256)
        s += -logf(fminf(rows1[i], 1.f)) - logf(fminf(rows2[i], 1.f));
    for (int off = 32; off; off >>= 1) s += __shfl_down(s, off);
    if ((threadIdx.x & 63) == 0) part[threadIdx.x >> 6] = s;
    __syncthreads();
    if (threadIdx.x == 0) {
        out[1] = (part[0] + part[1] + part[2] + part[3]) * (1.f / (float)B_LAB);
        out[0] = ce_acc[0] * (1.f / ((float)B_LAB * (float)CDIM));
    }
}

// ---------------------------------------------------------------------------
extern "C" void kernel_launch(void* const* d_in, const int* in_sizes, int n_in,
                              void* d_out, int out_size, void* d_ws, size_t ws_size,
                              hipStream_t stream)
{
    const float* x    = (const float*)d_in[0];
    const int*   y    = (const int*)  d_in[1];
    const float* xu   = (const float*)d_in[2];
    const int*   aidx = (const int*)  d_in[3];
    const int*   nidx = (const int*)  d_in[5];
    const float* W1 = (const float*)d_in[7];
    const float* b1 = (const float*)d_in[8];
    const float* W2 = (const float*)d_in[9];
    const float* b2 = (const float*)d_in[10];
    const float* W3 = (const float*)d_in[11];
    const float* b3 = (const float*)d_in[12];

    char* ws = (char*)d_ws;
    unsigned short* XB   = (unsigned short*)(ws + OFF_XB);
    unsigned short* W1B  = (unsigned short*)(ws + OFF_W1B);
    unsigned short* H1B  = (unsigned short*)(ws + OFF_H1B);
    unsigned short* LPb  = (unsigned short*)(ws + OFF_LPB);
    unsigned short* L1Pb = (unsigned short*)(ws + OFF_L1PB);
    unsigned short* MAB  = (unsigned short*)(ws + OFF_MAB);
    unsigned short* MNB  = (unsigned short*)(ws + OFF_MNB);
    unsigned short* W2B  = (unsigned short*)(ws + OFF_W2B);
    unsigned short* W3B  = (unsigned short*)(ws + OFF_W3B);
    unsigned short* H2B  = (unsigned short*)(ws + OFF_H2B);
    float* ROWS = (float*)(ws + OFF_ROWS);
    float* ACC  = ROWS + 2 * B_TOT;
    float* out  = (float*)d_out;

    // all prep work in one launch (counts, conversions, zeroing)
    prep<<<2163, 256, 0, stream>>>(aidx, nidx, x, xu, W1, W2, W3,
                                   MAB, MNB, XB, W1B, W2B, W3B, ROWS);

    // MLP on matrix cores
    mfma_gemm<1><<<dim3(H1DIM / 64, B_TOT / 64), 256, 0, stream>>>(
        XB, W1B, b1, H1B, B_TOT, H1DIM, DPAD);
    mfma_gemm<1><<<dim3(H2DIM / 64, B_TOT / 64), 256, 0, stream>>>(
        H1B, W2B, b2, H2B, B_TOT, H2DIM, H1DIM);
    gemm3_fused<<<dim3(CDIM / 64, B_TOT / 64), 256, 0, stream>>>(
        H2B, W3B, b3, y, LPb, L1Pb, ACC);

    // semantic loss GEMM (both branches via blockIdx.z), 2-phase pipelined
    sem_gemm<<<dim3(CDIM / 128, B_TOT / 128, 2), 256, 0, stream>>>(
        LPb, L1Pb, MAB, MNB, ROWS, ROWS + B_TOT);
    final_kernel<<<1, 256, 0, stream>>>(ROWS, ROWS + B_TOT, ACC, out);
}